// Round 12
// baseline (455.107 us; speedup 1.0000x reference)
//
#include <hip/hip_runtime.h>
#include <cstdint>
#include <cstddef>

static constexpr int HID = 128;
static constexpr int TASKS = 12;

using short8 = __attribute__((ext_vector_type(8))) short;  // 8 bf16 (4 VGPRs)
using f32x4  = __attribute__((ext_vector_type(4))) float;  // MFMA accumulator

__device__ inline unsigned short f2bf(float f) {
    union { float f; unsigned u; } v{f};
    unsigned r = v.u + 0x7fff + ((v.u >> 16) & 1);  // RNE
    return (unsigned short)(r >> 16);
}
__device__ inline float bf2f(unsigned short b) {
    union { unsigned u; float f; } v{(unsigned)b << 16};
    return v.f;
}

// ---------------- index dtype detection ----------------
__global__ void detect_i64(const unsigned int* __restrict__ ebuf, int* __restrict__ flag) {
    __shared__ unsigned int sh[256];
    const int t = threadIdx.x;
    unsigned int v = 0;
    for (int i = t; i < 1024; i += 256) v |= ebuf[2 * i + 1];
    sh[t] = v;
    __syncthreads();
    for (int s = 128; s > 0; s >>= 1) {
        if (t < s) sh[t] |= sh[t + s];
        __syncthreads();
    }
    if (t == 0) flag[0] = (sh[0] == 0u) ? 1 : 0;
}

__global__ void convert_batch(const void* __restrict__ bbuf, const int* __restrict__ flag,
                              int* __restrict__ b32, int N) {
    const int i = blockIdx.x * blockDim.x + threadIdx.x;
    if (i >= N) return;
    b32[i] = (*flag) ? (int)((const long long*)bbuf)[i] : ((const int*)bbuf)[i];
}

// ---------------- CSR build, phase 1: LDS-binned edge partition ----------------
// Buckets of 256 consecutive dst nodes (bucket = dst>>8; requires N <= 131072).
// Packed entry: (dst&255)<<24 | src  (src < 2^24). One global atomic per
// (block,bucket); coalesced copy-out into per-bucket global segments.
__global__ __launch_bounds__(256) void bin_convert(const void* __restrict__ ebuf,
                                                   const int* __restrict__ flag,
                                                   unsigned* __restrict__ pairs,
                                                   int* __restrict__ bucket_fill,
                                                   int E, int CAP) {
    constexpr int EPB = 4096, EPT = 16;
    __shared__ int cnt[512];
    __shared__ int base_[512];
    __shared__ int gb[512];
    __shared__ int s2[256];
    __shared__ unsigned lp[EPB];
    const int t = threadIdx.x;
    const int start = blockIdx.x * EPB;
    const int nE = min(EPB, E - start);
    cnt[t] = 0;
    cnt[t + 256] = 0;
    __syncthreads();

    unsigned pk[EPT];
    unsigned short bk[EPT], loc[EPT];
    const bool is64 = (*flag != 0);
#pragma unroll
    for (int j = 0; j < EPT; ++j) {
        const int i = start + t + j * 256;
        if (i - start < nE) {
            unsigned ss, dd;
            if (is64) {
                ss = (unsigned)((const long long*)ebuf)[i];
                dd = (unsigned)((const long long*)ebuf)[(size_t)E + i];
            } else {
                ss = ((const unsigned*)ebuf)[i];
                dd = ((const unsigned*)ebuf)[(size_t)E + i];
            }
            const int b = dd >> 8;
            pk[j] = ((dd & 255u) << 24) | ss;
            bk[j] = (unsigned short)b;
            loc[j] = (unsigned short)atomicAdd(&cnt[b], 1);
        }
    }
    __syncthreads();
    // exclusive scan of 512 bucket counts by 256 threads (2 per thread)
    const int a = cnt[2 * t], b_ = cnt[2 * t + 1];
    s2[t] = a + b_;
    __syncthreads();
    for (int off = 1; off < 256; off <<= 1) {
        const int x = (t >= off) ? s2[t - off] : 0;
        __syncthreads();
        s2[t] += x;
        __syncthreads();
    }
    const int ex = s2[t] - a - b_;
    base_[2 * t] = ex;
    base_[2 * t + 1] = ex + a;
    __syncthreads();
    // reorder into LDS, bucket-grouped
#pragma unroll
    for (int j = 0; j < EPT; ++j) {
        const int i = start + t + j * 256;
        if (i - start < nE) lp[base_[bk[j]] + loc[j]] = pk[j];
    }
    // reserve global segment space: one atomic per non-empty bucket
    for (int b = t; b < 512; b += 256) {
        const int c = cnt[b];
        gb[b] = c ? atomicAdd(&bucket_fill[b], c) : 0;
    }
    __syncthreads();
    // locate bucket of each LDS slot via binary search over base_ (coalesced out)
    for (int i = t; i < nE; i += 256) {
        int lo = 0, hi = 511;
        while (lo < hi) {  // find last bucket with base_ <= i
            const int mid = (lo + hi + 1) >> 1;
            if (base_[mid] <= i) lo = mid; else hi = mid - 1;
        }
        pairs[(size_t)lo * CAP + gb[lo] + (i - base_[lo])] = lp[i];
    }
}

// ---------------- CSR build, phase 2: per-bucket scatter (L2-local) ----------------
__global__ __launch_bounds__(256) void bucket_scatter(const unsigned* __restrict__ pairs,
                                                      const int* __restrict__ bucket_fill,
                                                      int* __restrict__ rowbeg,
                                                      int* __restrict__ degO,
                                                      unsigned* __restrict__ csrb,
                                                      int N, int CAP) {
    const int b = blockIdx.x;
    const int t = threadIdx.x;
    const int d0 = b << 8;
    const int cnt = bucket_fill[b];
    const size_t seg = (size_t)b * CAP;
    __shared__ int degw[256];
    __shared__ int offw[256];
    __shared__ int frw[256];
    degw[t] = 0;
    __syncthreads();
    for (int i = t; i < cnt; i += 256) {
        atomicAdd(&degw[pairs[seg + i] >> 24], 1);
    }
    __syncthreads();
    const int v = degw[t];
    offw[t] = v;
    __syncthreads();
    for (int off = 1; off < 256; off <<= 1) {
        const int x = (t >= off) ? offw[t - off] : 0;
        __syncthreads();
        offw[t] += x;
        __syncthreads();
    }
    const int ex = offw[t] - v;
    const int node = d0 + t;
    if (node < N) {
        rowbeg[node] = (int)(seg + ex);
        degO[node] = v;
    }
    frw[t] = ex;
    __syncthreads();
    for (int i = t; i < cnt; i += 256) {
        const unsigned p = pairs[seg + i];
        const int pos = atomicAdd(&frw[p >> 24], 1);
        csrb[seg + pos] = p & 0x00FFFFFFu;
    }
}

// ---------------- dtype conversions ----------------
// x f32 [N][64] -> compact bf16 [N][64]
__global__ void cvt_x(const float* __restrict__ x, unsigned short* __restrict__ hx, int N) {
    const int idx = blockIdx.x * blockDim.x + threadIdx.x;
    if (idx >= N * 16) return;
    const int n = idx >> 4;
    const int k4 = (idx & 15) * 4;
    const float4 v = *reinterpret_cast<const float4*>(x + (size_t)n * 64 + k4);
    ushort4 o;
    o.x = f2bf(v.x); o.y = f2bf(v.y); o.z = f2bf(v.z); o.w = f2bf(v.w);
    *reinterpret_cast<ushort4*>(hx + (size_t)n * 64 + k4) = o;
}

// all three weight pairs -> concatenated bf16 [128][2*KH] each, one launch
__global__ void cvt_w3(const float* __restrict__ Wl1, const float* __restrict__ Wr1,
                       const float* __restrict__ Wl2, const float* __restrict__ Wr2,
                       const float* __restrict__ Wl3, const float* __restrict__ Wr3,
                       unsigned short* __restrict__ wc1, unsigned short* __restrict__ wc2,
                       unsigned short* __restrict__ wc3) {
    const int idx = blockIdx.x * blockDim.x + threadIdx.x;  // 81920 total
    if (idx < 128 * 128) {
        const int j = idx >> 7, k = idx & 127;           // K2=128, KH=64
        const float v = (k < 64) ? Wl1[j * 64 + k] : Wr1[j * 64 + k - 64];
        wc1[idx] = f2bf(v);
    } else if (idx < 128 * 128 + 128 * 256) {
        const int r = idx - 128 * 128;
        const int j = r >> 8, k = r & 255;               // K2=256, KH=128
        const float v = (k < 128) ? Wl2[j * 128 + k] : Wr2[j * 128 + k - 128];
        wc2[r] = f2bf(v);
    } else if (idx < 128 * 128 + 2 * 128 * 256) {
        const int r = idx - 128 * 128 - 128 * 256;
        const int j = r >> 8, k = r & 255;
        const float v = (k < 128) ? Wl3[j * 128 + k] : Wr3[j * 128 + k - 128];
        wc3[r] = f2bf(v);
    }
}

// ---------------- mean aggregation (bf16, compact stride=D) ----------------
template <int D>
__global__ __launch_bounds__(256) void agg_bf16(const unsigned short* __restrict__ src,
                                                unsigned short* __restrict__ dst,
                                                const int* __restrict__ rowbeg,
                                                const int* __restrict__ degO,
                                                const unsigned* __restrict__ csrb, int N) {
    constexpr int LPR = D * 2 / 16;       // lanes per row (16B each): 16 for D=128, 8 for D=64
    constexpr int RPI = 64 / LPR;         // rows per iteration: 4 or 8
    const int gid = blockIdx.x * blockDim.x + threadIdx.x;
    const int node = gid >> 6;
    const int lane = gid & 63;
    if (node >= N) return;
    const int beg = rowbeg[node];
    const int dg = degO[node];
    const int end = beg + dg;
    const int g = lane / LPR;
    const int m = lane % LPR;

    float acc[8] = {0.f, 0.f, 0.f, 0.f, 0.f, 0.f, 0.f, 0.f};

    for (int k = beg + g; k < end; k += RPI) {
        const int s = (int)csrb[k];
        const short8 v = *reinterpret_cast<const short8*>(src + (size_t)s * D + m * 8);
        const unsigned* u = reinterpret_cast<const unsigned*>(&v);
#pragma unroll
        for (int j = 0; j < 4; ++j) {
            union { unsigned u; float f; } lo{u[j] << 16}, hi{u[j] & 0xffff0000u};
            acc[2 * j]     += lo.f;
            acc[2 * j + 1] += hi.f;
        }
    }

#pragma unroll
    for (int mask = LPR; mask < 64; mask <<= 1) {
#pragma unroll
        for (int j = 0; j < 8; ++j) acc[j] += __shfl_xor(acc[j], mask);
    }

    if (lane < LPR) {
        const float inv = 1.0f / fmaxf((float)dg, 1.0f);
        unsigned o[4];
#pragma unroll
        for (int j = 0; j < 4; ++j) {
            o[j] = ((unsigned)f2bf(acc[2 * j + 1] * inv) << 16) | (unsigned)f2bf(acc[2 * j] * inv);
        }
        *reinterpret_cast<uint4*>(dst + (size_t)node * D + m * 8) =
            make_uint4(o[0], o[1], o[2], o[3]);
    }
}

// ---------------- MFMA GEMM: OUT = relu([A0|A1] @ W^T + b), split-K input ----------------
// A0, A1 compact [N][DIN] bf16; W [128][2*DIN] bf16; OUT compact [N][128] bf16.
template <int DIN>
__global__ __launch_bounds__(256) void mfma_gemm(const unsigned short* __restrict__ A0,
                                                 const unsigned short* __restrict__ A1,
                                                 const unsigned short* __restrict__ W,
                                                 const float* __restrict__ bias,
                                                 unsigned short* __restrict__ OUT,
                                                 int N) {
    constexpr int K2 = 2 * DIN;
    const int tid = threadIdx.x;
    const int wid = tid >> 6;
    const int lane = tid & 63;
    const int m0 = blockIdx.x * 128;
    const int wm = m0 + wid * 32;
    const int lrow = lane & 15;
    const int kb = (lane >> 4) * 8;

    f32x4 acc[2][8];
#pragma unroll
    for (int i = 0; i < 2; ++i)
#pragma unroll
        for (int j = 0; j < 8; ++j) acc[i][j] = {0.f, 0.f, 0.f, 0.f};

    const int arow0 = wm + lrow;
    const int arow1 = wm + 16 + lrow;

#pragma unroll
    for (int k0 = 0; k0 < K2; k0 += 32) {
        const unsigned short* __restrict__ Ap = (k0 < DIN) ? A0 : A1;
        const int kc = (k0 < DIN) ? k0 : (k0 - DIN);
        short8 a0 = {0, 0, 0, 0, 0, 0, 0, 0}, a1 = a0;
        if (arow0 < N) a0 = *reinterpret_cast<const short8*>(Ap + (size_t)arow0 * DIN + kc + kb);
        if (arow1 < N) a1 = *reinterpret_cast<const short8*>(Ap + (size_t)arow1 * DIN + kc + kb);
        short8 b[8];
#pragma unroll
        for (int jb = 0; jb < 8; ++jb) {
            const int wrow = jb * 16 + lrow;
            b[jb] = *reinterpret_cast<const short8*>(W + (size_t)wrow * K2 + k0 + kb);
        }
#pragma unroll
        for (int jb = 0; jb < 8; ++jb) {
            acc[0][jb] = __builtin_amdgcn_mfma_f32_16x16x32_bf16(a0, b[jb], acc[0][jb], 0, 0, 0);
            acc[1][jb] = __builtin_amdgcn_mfma_f32_16x16x32_bf16(a1, b[jb], acc[1][jb], 0, 0, 0);
        }
    }

    float bias_r[8];
#pragma unroll
    for (int jb = 0; jb < 8; ++jb) bias_r[jb] = bias[jb * 16 + lrow];

    const int rbase = (lane >> 4) * 4;
#pragma unroll
    for (int i = 0; i < 2; ++i) {
#pragma unroll
        for (int r = 0; r < 4; ++r) {
            const int row = wm + i * 16 + rbase + r;
            if (row < N) {
                unsigned short* o = OUT + (size_t)row * HID + lrow;
#pragma unroll
                for (int jb = 0; jb < 8; ++jb) {
                    const float v = fmaxf(acc[i][jb][r] + bias_r[jb], 0.f);
                    o[jb * 16] = f2bf(v);
                }
            }
        }
    }
}

// ---------------- global mean pool + output head ----------------
__global__ __launch_bounds__(128) void pool_kernel(const unsigned short* __restrict__ H,
                                                   const int* __restrict__ batch,
                                                   const float* __restrict__ Wout,
                                                   const float* __restrict__ bout,
                                                   float* __restrict__ out, int N, int G) {
    const int g = blockIdx.x;
    const int t = threadIdx.x;
    int lo = 0, hi = N;
    while (lo < hi) {
        const int mid = (lo + hi) >> 1;
        if (batch[mid] < g) lo = mid + 1; else hi = mid;
    }
    const int start = lo;
    hi = N;
    while (lo < hi) {
        const int mid = (lo + hi) >> 1;
        if (batch[mid] < g + 1) lo = mid + 1; else hi = mid;
    }
    const int end = lo;
    float acc = 0.f;
    for (int n = start; n < end; ++n) acc += bf2f(H[(size_t)n * HID + t]);
    const float inv = 1.0f / fmaxf((float)(end - start), 1.0f);
    __shared__ float pl[HID];
    pl[t] = acc * inv;
    __syncthreads();
    if (t < TASKS) {
        float dot = bout[t];
        const float* w = Wout + t * HID;
        for (int k = 0; k < HID; ++k) dot = fmaf(pl[k], w[k], dot);
        out[(size_t)g * TASKS + t] = dot;
    }
}

// ---------------- launcher ----------------
extern "C" void kernel_launch(void* const* d_in, const int* in_sizes, int n_in,
                              void* d_out, int out_size, void* d_ws, size_t ws_size,
                              hipStream_t stream) {
    const float* x    = (const float*)d_in[0];
    const void*  e    = d_in[1];
    const void*  bt   = d_in[2];
    const float* Wl1  = (const float*)d_in[3];
    const float* bl1  = (const float*)d_in[4];
    const float* Wr1  = (const float*)d_in[5];
    const float* Wl2  = (const float*)d_in[6];
    const float* bl2  = (const float*)d_in[7];
    const float* Wr2  = (const float*)d_in[8];
    const float* Wl3  = (const float*)d_in[9];
    const float* bl3  = (const float*)d_in[10];
    const float* Wr3  = (const float*)d_in[11];
    const float* Wout = (const float*)d_in[12];
    const float* bout = (const float*)d_in[13];
    float* out = (float*)d_out;

    const int N = in_sizes[0] / 64;   // requires N <= 131072 (bucket = dst>>8) and N < 2^24 (packing)
    const int E = in_sizes[1] / 2;
    const int G = out_size / TASKS;
    const int NB = (N + 255) >> 8;
    const int CAP = 6144;             // per-bucket capacity; mean ~3200 for this input, +52 sigma

    char* base = (char*)d_ws;
    size_t off = 0;
    auto alloc = [&](size_t bytes) -> void* {
        void* p = base + off;
        off += (bytes + 255) & ~(size_t)255;
        return p;
    };
    int* flag        = (int*)alloc(256);
    int* b32         = (int*)alloc((size_t)N * 4);
    int* bucket_fill = (int*)alloc((size_t)NB * 4);
    int* rowbeg      = (int*)alloc((size_t)N * 4);
    int* degO        = (int*)alloc((size_t)N * 4);
    unsigned* pairs  = (unsigned*)alloc((size_t)NB * CAP * 4);
    unsigned* csrb   = (unsigned*)alloc((size_t)NB * CAP * 4);
    unsigned short* wc1 = (unsigned short*)alloc((size_t)128 * 128 * 2);
    unsigned short* wc2 = (unsigned short*)alloc((size_t)128 * 256 * 2);
    unsigned short* wc3 = (unsigned short*)alloc((size_t)128 * 256 * 2);
    unsigned short* hx = (unsigned short*)alloc((size_t)N * 64 * 2);    // compact x
    unsigned short* a1 = (unsigned short*)alloc((size_t)N * 64 * 2);    // compact agg1
    unsigned short* h1 = (unsigned short*)alloc((size_t)N * 128 * 2);
    unsigned short* a2 = (unsigned short*)alloc((size_t)N * 128 * 2);
    unsigned short* h2 = (unsigned short*)alloc((size_t)N * 128 * 2);
    unsigned short* a3 = (unsigned short*)alloc((size_t)N * 128 * 2);
    unsigned short* h3 = (unsigned short*)alloc((size_t)N * 128 * 2);
    (void)ws_size;
    (void)n_in;

    hipMemsetAsync(bucket_fill, 0, (size_t)NB * 4, stream);

    detect_i64<<<1, 256, 0, stream>>>((const unsigned int*)e, flag);
    convert_batch<<<(N + 255) / 256, 256, 0, stream>>>(bt, flag, b32, N);
    bin_convert<<<(E + 4095) / 4096, 256, 0, stream>>>(e, flag, pairs, bucket_fill, E, CAP);
    bucket_scatter<<<NB, 256, 0, stream>>>(pairs, bucket_fill, rowbeg, degO, csrb, N, CAP);

    cvt_x<<<(N * 16 + 255) / 256, 256, 0, stream>>>(x, hx, N);
    cvt_w3<<<(81920 + 255) / 256, 256, 0, stream>>>(Wl1, Wr1, Wl2, Wr2, Wl3, Wr3, wc1, wc2, wc3);

    const int aggBlocks = (int)(((size_t)N * 64 + 255) / 256);
    const int gemmBlocks = (N + 127) / 128;

    // layer 1
    agg_bf16<64><<<aggBlocks, 256, 0, stream>>>(hx, a1, rowbeg, degO, csrb, N);
    mfma_gemm<64><<<gemmBlocks, 256, 0, stream>>>(hx, a1, wc1, bl1, h1, N);
    // layer 2
    agg_bf16<128><<<aggBlocks, 256, 0, stream>>>(h1, a2, rowbeg, degO, csrb, N);
    mfma_gemm<128><<<gemmBlocks, 256, 0, stream>>>(h1, a2, wc2, bl2, h2, N);
    // layer 3
    agg_bf16<128><<<aggBlocks, 256, 0, stream>>>(h2, a3, rowbeg, degO, csrb, N);
    mfma_gemm<128><<<gemmBlocks, 256, 0, stream>>>(h2, a3, wc3, bl3, h3, N);

    pool_kernel<<<G, 128, 0, stream>>>(h3, b32, Wout, bout, out, N, G);
}

// Round 14
// 442.799 us; speedup vs baseline: 1.0278x; 1.0278x over previous
//
#include <hip/hip_runtime.h>
#include <cstdint>
#include <cstddef>

static constexpr int HID = 128;
static constexpr int TASKS = 12;

using short8 = __attribute__((ext_vector_type(8))) short;  // 8 bf16 (4 VGPRs)
using f32x4  = __attribute__((ext_vector_type(4))) float;  // MFMA accumulator

__device__ inline unsigned short f2bf(float f) {
    union { float f; unsigned u; } v{f};
    unsigned r = v.u + 0x7fff + ((v.u >> 16) & 1);  // RNE
    return (unsigned short)(r >> 16);
}
__device__ inline float bf2f(unsigned short b) {
    union { unsigned u; float f; } v{(unsigned)b << 16};
    return v.f;
}

// ---------------- index dtype detection ----------------
__global__ void detect_i64(const unsigned int* __restrict__ ebuf, int* __restrict__ flag) {
    __shared__ unsigned int sh[256];
    const int t = threadIdx.x;
    unsigned int v = 0;
    for (int i = t; i < 1024; i += 256) v |= ebuf[2 * i + 1];
    sh[t] = v;
    __syncthreads();
    for (int s = 128; s > 0; s >>= 1) {
        if (t < s) sh[t] |= sh[t + s];
        __syncthreads();
    }
    if (t == 0) flag[0] = (sh[0] == 0u) ? 1 : 0;
}

__global__ void convert_batch(const void* __restrict__ bbuf, const int* __restrict__ flag,
                              int* __restrict__ b32, int N) {
    const int i = blockIdx.x * blockDim.x + threadIdx.x;
    if (i >= N) return;
    b32[i] = (*flag) ? (int)((const long long*)bbuf)[i] : ((const int*)bbuf)[i];
}

// ---------------- CSR build, phase 1: LDS-binned edge partition ----------------
__global__ __launch_bounds__(256) void bin_convert(const void* __restrict__ ebuf,
                                                   const int* __restrict__ flag,
                                                   unsigned* __restrict__ pairs,
                                                   int* __restrict__ bucket_fill,
                                                   int E, int CAP) {
    constexpr int EPB = 4096, EPT = 16;
    __shared__ int cnt[512];
    __shared__ int base_[512];
    __shared__ int gb[512];
    __shared__ int s2[256];
    __shared__ unsigned lp[EPB];
    const int t = threadIdx.x;
    const int start = blockIdx.x * EPB;
    const int nE = min(EPB, E - start);
    cnt[t] = 0;
    cnt[t + 256] = 0;
    __syncthreads();

    unsigned pk[EPT];
    unsigned short bk[EPT], loc[EPT];
    const bool is64 = (*flag != 0);
#pragma unroll
    for (int j = 0; j < EPT; ++j) {
        const int i = start + t + j * 256;
        if (i - start < nE) {
            unsigned ss, dd;
            if (is64) {
                ss = (unsigned)((const long long*)ebuf)[i];
                dd = (unsigned)((const long long*)ebuf)[(size_t)E + i];
            } else {
                ss = ((const unsigned*)ebuf)[i];
                dd = ((const unsigned*)ebuf)[(size_t)E + i];
            }
            const int b = dd >> 8;
            pk[j] = ((dd & 255u) << 24) | ss;
            bk[j] = (unsigned short)b;
            loc[j] = (unsigned short)atomicAdd(&cnt[b], 1);
        }
    }
    __syncthreads();
    // exclusive scan of 512 bucket counts by 256 threads (2 per thread)
    const int a = cnt[2 * t], b_ = cnt[2 * t + 1];
    s2[t] = a + b_;
    __syncthreads();
    for (int off = 1; off < 256; off <<= 1) {
        const int x = (t >= off) ? s2[t - off] : 0;
        __syncthreads();
        s2[t] += x;
        __syncthreads();
    }
    const int ex = s2[t] - a - b_;
    base_[2 * t] = ex;
    base_[2 * t + 1] = ex + a;
    __syncthreads();
    // reorder into LDS, bucket-grouped
#pragma unroll
    for (int j = 0; j < EPT; ++j) {
        const int i = start + t + j * 256;
        if (i - start < nE) lp[base_[bk[j]] + loc[j]] = pk[j];
    }
    // reserve global segment space: one atomic per non-empty bucket
    for (int b = t; b < 512; b += 256) {
        const int c = cnt[b];
        gb[b] = c ? atomicAdd(&bucket_fill[b], c) : 0;
    }
    __syncthreads();
    // locate bucket of each LDS slot via binary search over base_ (coalesced out)
    for (int i = t; i < nE; i += 256) {
        int lo = 0, hi = 511;
        while (lo < hi) {  // find last bucket with base_ <= i
            const int mid = (lo + hi + 1) >> 1;
            if (base_[mid] <= i) lo = mid; else hi = mid - 1;
        }
        pairs[(size_t)lo * CAP + gb[lo] + (i - base_[lo])] = lp[i];
    }
}

// ---------------- CSR build, phase 2: per-bucket scatter (L2-local) ----------------
__global__ __launch_bounds__(256) void bucket_scatter(const unsigned* __restrict__ pairs,
                                                      const int* __restrict__ bucket_fill,
                                                      int* __restrict__ rowbeg,
                                                      int* __restrict__ degO,
                                                      unsigned* __restrict__ csrb,
                                                      int N, int CAP) {
    const int b = blockIdx.x;
    const int t = threadIdx.x;
    const int d0 = b << 8;
    const int cnt = bucket_fill[b];
    const size_t seg = (size_t)b * CAP;
    __shared__ int degw[256];
    __shared__ int offw[256];
    __shared__ int frw[256];
    degw[t] = 0;
    __syncthreads();
    for (int i = t; i < cnt; i += 256) {
        atomicAdd(&degw[pairs[seg + i] >> 24], 1);
    }
    __syncthreads();
    const int v = degw[t];
    offw[t] = v;
    __syncthreads();
    for (int off = 1; off < 256; off <<= 1) {
        const int x = (t >= off) ? offw[t - off] : 0;
        __syncthreads();
        offw[t] += x;
        __syncthreads();
    }
    const int ex = offw[t] - v;
    const int node = d0 + t;
    if (node < N) {
        rowbeg[node] = (int)(seg + ex);
        degO[node] = v;
    }
    frw[t] = ex;
    __syncthreads();
    for (int i = t; i < cnt; i += 256) {
        const unsigned p = pairs[seg + i];
        const int pos = atomicAdd(&frw[p >> 24], 1);
        csrb[seg + pos] = p & 0x00FFFFFFu;
    }
}

// ---------------- dtype conversions ----------------
__global__ void cvt_x(const float* __restrict__ x, unsigned short* __restrict__ hx, int N) {
    const int idx = blockIdx.x * blockDim.x + threadIdx.x;
    if (idx >= N * 16) return;
    const int n = idx >> 4;
    const int k4 = (idx & 15) * 4;
    const float4 v = *reinterpret_cast<const float4*>(x + (size_t)n * 64 + k4);
    ushort4 o;
    o.x = f2bf(v.x); o.y = f2bf(v.y); o.z = f2bf(v.z); o.w = f2bf(v.w);
    *reinterpret_cast<ushort4*>(hx + (size_t)n * 64 + k4) = o;
}

__global__ void cvt_w3(const float* __restrict__ Wl1, const float* __restrict__ Wr1,
                       const float* __restrict__ Wl2, const float* __restrict__ Wr2,
                       const float* __restrict__ Wl3, const float* __restrict__ Wr3,
                       unsigned short* __restrict__ wc1, unsigned short* __restrict__ wc2,
                       unsigned short* __restrict__ wc3) {
    const int idx = blockIdx.x * blockDim.x + threadIdx.x;  // 81920 total
    if (idx < 128 * 128) {
        const int j = idx >> 7, k = idx & 127;           // K2=128, KH=64
        const float v = (k < 64) ? Wl1[j * 64 + k] : Wr1[j * 64 + k - 64];
        wc1[idx] = f2bf(v);
    } else if (idx < 128 * 128 + 128 * 256) {
        const int r = idx - 128 * 128;
        const int j = r >> 8, k = r & 255;               // K2=256, KH=128
        const float v = (k < 128) ? Wl2[j * 128 + k] : Wr2[j * 128 + k - 128];
        wc2[r] = f2bf(v);
    } else if (idx < 128 * 128 + 2 * 128 * 256) {
        const int r = idx - 128 * 128 - 128 * 256;
        const int j = r >> 8, k = r & 255;
        const float v = (k < 128) ? Wl3[j * 128 + k] : Wr3[j * 128 + k - 128];
        wc3[r] = f2bf(v);
    }
}

// ---------------- mean aggregation (bf16, compact stride=D), 16-rows-in-flight ----------------
// One wave per node. Per pass: 16 rows covered by GRP row-groups x J independent
// predicated loads per lane -> 16 memory segments in flight per wave (vs 4 before).
template <int D>
__global__ __launch_bounds__(256) void agg_bf16(const unsigned short* __restrict__ src,
                                                unsigned short* __restrict__ dst,
                                                const int* __restrict__ rowbeg,
                                                const int* __restrict__ degO,
                                                const unsigned* __restrict__ csrb, int N) {
    constexpr int LPR = D / 8;            // lanes per row (8 bf16 = 16B each): 16 (D=128), 8 (D=64)
    constexpr int GRP = 64 / LPR;         // row groups per pass: 4, 8
    constexpr int J = 16 / GRP;           // independent loads per lane per pass: 4, 2
    const int gid = blockIdx.x * blockDim.x + threadIdx.x;
    const int node = gid >> 6;
    const int lane = gid & 63;
    if (node >= N) return;
    const int beg = rowbeg[node];
    const int dg = degO[node];
    const int end = beg + dg;
    const int g = lane / LPR;
    const int m = lane % LPR;

    float acc[8] = {0.f, 0.f, 0.f, 0.f, 0.f, 0.f, 0.f, 0.f};

    for (int k0 = beg; k0 < end; k0 += 16) {
        short8 v[J];
#pragma unroll
        for (int j = 0; j < J; ++j) {
            const int kk = k0 + g + j * GRP;
            v[j] = short8{0, 0, 0, 0, 0, 0, 0, 0};
            if (kk < end) {
                const int s = (int)csrb[kk];
                v[j] = *reinterpret_cast<const short8*>(src + (size_t)s * D + m * 8);
            }
        }
#pragma unroll
        for (int j = 0; j < J; ++j) {
            const unsigned* u = reinterpret_cast<const unsigned*>(&v[j]);
#pragma unroll
            for (int q = 0; q < 4; ++q) {
                union { unsigned u; float f; } lo{u[q] << 16}, hi{u[q] & 0xffff0000u};
                acc[2 * q]     += lo.f;
                acc[2 * q + 1] += hi.f;
            }
        }
    }

    // reduce across row-groups (high lane bits above LPR)
#pragma unroll
    for (int mask = LPR; mask < 64; mask <<= 1) {
#pragma unroll
        for (int j = 0; j < 8; ++j) acc[j] += __shfl_xor(acc[j], mask);
    }

    if (lane < LPR) {
        const float inv = 1.0f / fmaxf((float)dg, 1.0f);
        unsigned o[4];
#pragma unroll
        for (int j = 0; j < 4; ++j) {
            o[j] = ((unsigned)f2bf(acc[2 * j + 1] * inv) << 16) | (unsigned)f2bf(acc[2 * j] * inv);
        }
        *reinterpret_cast<uint4*>(dst + (size_t)node * D + m * 8) =
            make_uint4(o[0], o[1], o[2], o[3]);
    }
}

// ---------------- MFMA GEMM: OUT = relu([A0|A1] @ W^T + b), split-K input ----------------
template <int DIN>
__global__ __launch_bounds__(256) void mfma_gemm(const unsigned short* __restrict__ A0,
                                                 const unsigned short* __restrict__ A1,
                                                 const unsigned short* __restrict__ W,
                                                 const float* __restrict__ bias,
                                                 unsigned short* __restrict__ OUT,
                                                 int N) {
    constexpr int K2 = 2 * DIN;
    const int tid = threadIdx.x;
    const int wid = tid >> 6;
    const int lane = tid & 63;
    const int m0 = blockIdx.x * 128;
    const int wm = m0 + wid * 32;
    const int lrow = lane & 15;
    const int kb = (lane >> 4) * 8;

    f32x4 acc[2][8];
#pragma unroll
    for (int i = 0; i < 2; ++i)
#pragma unroll
        for (int j = 0; j < 8; ++j) acc[i][j] = {0.f, 0.f, 0.f, 0.f};

    const int arow0 = wm + lrow;
    const int arow1 = wm + 16 + lrow;

#pragma unroll
    for (int k0 = 0; k0 < K2; k0 += 32) {
        const unsigned short* __restrict__ Ap = (k0 < DIN) ? A0 : A1;
        const int kc = (k0 < DIN) ? k0 : (k0 - DIN);
        short8 a0 = {0, 0, 0, 0, 0, 0, 0, 0}, a1 = a0;
        if (arow0 < N) a0 = *reinterpret_cast<const short8*>(Ap + (size_t)arow0 * DIN + kc + kb);
        if (arow1 < N) a1 = *reinterpret_cast<const short8*>(Ap + (size_t)arow1 * DIN + kc + kb);
        short8 b[8];
#pragma unroll
        for (int jb = 0; jb < 8; ++jb) {
            const int wrow = jb * 16 + lrow;
            b[jb] = *reinterpret_cast<const short8*>(W + (size_t)wrow * K2 + k0 + kb);
        }
#pragma unroll
        for (int jb = 0; jb < 8; ++jb) {
            acc[0][jb] = __builtin_amdgcn_mfma_f32_16x16x32_bf16(a0, b[jb], acc[0][jb], 0, 0, 0);
            acc[1][jb] = __builtin_amdgcn_mfma_f32_16x16x32_bf16(a1, b[jb], acc[1][jb], 0, 0, 0);
        }
    }

    float bias_r[8];
#pragma unroll
    for (int jb = 0; jb < 8; ++jb) bias_r[jb] = bias[jb * 16 + lrow];

    const int rbase = (lane >> 4) * 4;
#pragma unroll
    for (int i = 0; i < 2; ++i) {
#pragma unroll
        for (int r = 0; r < 4; ++r) {
            const int row = wm + i * 16 + rbase + r;
            if (row < N) {
                unsigned short* o = OUT + (size_t)row * HID + lrow;
#pragma unroll
                for (int jb = 0; jb < 8; ++jb) {
                    const float v = fmaxf(acc[i][jb][r] + bias_r[jb], 0.f);
                    o[jb * 16] = f2bf(v);
                }
            }
        }
    }
}

// ---------------- global mean pool + output head ----------------
__global__ __launch_bounds__(128) void pool_kernel(const unsigned short* __restrict__ H,
                                                   const int* __restrict__ batch,
                                                   const float* __restrict__ Wout,
                                                   const float* __restrict__ bout,
                                                   float* __restrict__ out, int N, int G) {
    const int g = blockIdx.x;
    const int t = threadIdx.x;
    int lo = 0, hi = N;
    while (lo < hi) {
        const int mid = (lo + hi) >> 1;
        if (batch[mid] < g) lo = mid + 1; else hi = mid;
    }
    const int start = lo;
    hi = N;
    while (lo < hi) {
        const int mid = (lo + hi) >> 1;
        if (batch[mid] < g + 1) lo = mid + 1; else hi = mid;
    }
    const int end = lo;
    float acc = 0.f;
    for (int n = start; n < end; ++n) acc += bf2f(H[(size_t)n * HID + t]);
    const float inv = 1.0f / fmaxf((float)(end - start), 1.0f);
    __shared__ float pl[HID];
    pl[t] = acc * inv;
    __syncthreads();
    if (t < TASKS) {
        float dot = bout[t];
        const float* w = Wout + t * HID;
        for (int k = 0; k < HID; ++k) dot = fmaf(pl[k], w[k], dot);
        out[(size_t)g * TASKS + t] = dot;
    }
}

// ---------------- launcher ----------------
extern "C" void kernel_launch(void* const* d_in, const int* in_sizes, int n_in,
                              void* d_out, int out_size, void* d_ws, size_t ws_size,
                              hipStream_t stream) {
    const float* x    = (const float*)d_in[0];
    const void*  e    = d_in[1];
    const void*  bt   = d_in[2];
    const float* Wl1  = (const float*)d_in[3];
    const float* bl1  = (const float*)d_in[4];
    const float* Wr1  = (const float*)d_in[5];
    const float* Wl2  = (const float*)d_in[6];
    const float* bl2  = (const float*)d_in[7];
    const float* Wr2  = (const float*)d_in[8];
    const float* Wl3  = (const float*)d_in[9];
    const float* bl3  = (const float*)d_in[10];
    const float* Wr3  = (const float*)d_in[11];
    const float* Wout = (const float*)d_in[12];
    const float* bout = (const float*)d_in[13];
    float* out = (float*)d_out;

    const int N = in_sizes[0] / 64;   // requires N <= 131072 (bucket = dst>>8) and N < 2^24 (packing)
    const int E = in_sizes[1] / 2;
    const int G = out_size / TASKS;
    const int NB = (N + 255) >> 8;
    const int CAP = 6144;             // per-bucket capacity; mean ~3200 for this input, +52 sigma

    char* base = (char*)d_ws;
    size_t off = 0;
    auto alloc = [&](size_t bytes) -> void* {
        void* p = base + off;
        off += (bytes + 255) & ~(size_t)255;
        return p;
    };
    int* flag        = (int*)alloc(256);
    int* b32         = (int*)alloc((size_t)N * 4);
    int* bucket_fill = (int*)alloc((size_t)NB * 4);
    int* rowbeg      = (int*)alloc((size_t)N * 4);
    int* degO        = (int*)alloc((size_t)N * 4);
    unsigned* pairs  = (unsigned*)alloc((size_t)NB * CAP * 4);
    unsigned* csrb   = (unsigned*)alloc((size_t)NB * CAP * 4);
    unsigned short* wc1 = (unsigned short*)alloc((size_t)128 * 128 * 2);
    unsigned short* wc2 = (unsigned short*)alloc((size_t)128 * 256 * 2);
    unsigned short* wc3 = (unsigned short*)alloc((size_t)128 * 256 * 2);
    unsigned short* hx = (unsigned short*)alloc((size_t)N * 64 * 2);    // compact x
    unsigned short* a1 = (unsigned short*)alloc((size_t)N * 64 * 2);    // compact agg1
    unsigned short* h1 = (unsigned short*)alloc((size_t)N * 128 * 2);
    unsigned short* a2 = (unsigned short*)alloc((size_t)N * 128 * 2);
    unsigned short* h2 = (unsigned short*)alloc((size_t)N * 128 * 2);
    unsigned short* a3 = (unsigned short*)alloc((size_t)N * 128 * 2);
    unsigned short* h3 = (unsigned short*)alloc((size_t)N * 128 * 2);
    (void)ws_size;
    (void)n_in;

    hipMemsetAsync(bucket_fill, 0, (size_t)NB * 4, stream);

    detect_i64<<<1, 256, 0, stream>>>((const unsigned int*)e, flag);
    convert_batch<<<(N + 255) / 256, 256, 0, stream>>>(bt, flag, b32, N);
    bin_convert<<<(E + 4095) / 4096, 256, 0, stream>>>(e, flag, pairs, bucket_fill, E, CAP);
    bucket_scatter<<<NB, 256, 0, stream>>>(pairs, bucket_fill, rowbeg, degO, csrb, N, CAP);

    cvt_x<<<(N * 16 + 255) / 256, 256, 0, stream>>>(x, hx, N);
    cvt_w3<<<(81920 + 255) / 256, 256, 0, stream>>>(Wl1, Wr1, Wl2, Wr2, Wl3, Wr3, wc1, wc2, wc3);

    const int aggBlocks = (int)(((size_t)N * 64 + 255) / 256);
    const int gemmBlocks = (N + 127) / 128;

    // layer 1
    agg_bf16<64><<<aggBlocks, 256, 0, stream>>>(hx, a1, rowbeg, degO, csrb, N);
    mfma_gemm<64><<<gemmBlocks, 256, 0, stream>>>(hx, a1, wc1, bl1, h1, N);
    // layer 2
    agg_bf16<128><<<aggBlocks, 256, 0, stream>>>(h1, a2, rowbeg, degO, csrb, N);
    mfma_gemm<128><<<gemmBlocks, 256, 0, stream>>>(h1, a2, wc2, bl2, h2, N);
    // layer 3
    agg_bf16<128><<<aggBlocks, 256, 0, stream>>>(h2, a3, rowbeg, degO, csrb, N);
    mfma_gemm<128><<<gemmBlocks, 256, 0, stream>>>(h2, a3, wc3, bl3, h3, N);

    pool_kernel<<<G, 128, 0, stream>>>(h3, b32, Wout, bout, out, N, G);
}

// Round 15
// 432.081 us; speedup vs baseline: 1.0533x; 1.0248x over previous
//
#include <hip/hip_runtime.h>
#include <cstdint>
#include <cstddef>

static constexpr int HID = 128;
static constexpr int TASKS = 12;

using short8 = __attribute__((ext_vector_type(8))) short;  // 8 bf16 (4 VGPRs)
using f32x4  = __attribute__((ext_vector_type(4))) float;  // MFMA accumulator

__device__ inline unsigned short f2bf(float f) {
    union { float f; unsigned u; } v{f};
    unsigned r = v.u + 0x7fff + ((v.u >> 16) & 1);  // RNE
    return (unsigned short)(r >> 16);
}
__device__ inline float bf2f(unsigned short b) {
    union { unsigned u; float f; } v{(unsigned)b << 16};
    return v.f;
}

// ---------------- index dtype detection ----------------
__global__ void detect_i64(const unsigned int* __restrict__ ebuf, int* __restrict__ flag) {
    __shared__ unsigned int sh[256];
    const int t = threadIdx.x;
    unsigned int v = 0;
    for (int i = t; i < 1024; i += 256) v |= ebuf[2 * i + 1];
    sh[t] = v;
    __syncthreads();
    for (int s = 128; s > 0; s >>= 1) {
        if (t < s) sh[t] |= sh[t + s];
        __syncthreads();
    }
    if (t == 0) flag[0] = (sh[0] == 0u) ? 1 : 0;
}

__global__ void convert_batch(const void* __restrict__ bbuf, const int* __restrict__ flag,
                              int* __restrict__ b32, int N) {
    const int i = blockIdx.x * blockDim.x + threadIdx.x;
    if (i >= N) return;
    b32[i] = (*flag) ? (int)((const long long*)bbuf)[i] : ((const int*)bbuf)[i];
}

// ---------------- CSR build, phase 1: LDS-binned edge partition ----------------
__global__ __launch_bounds__(256) void bin_convert(const void* __restrict__ ebuf,
                                                   const int* __restrict__ flag,
                                                   unsigned* __restrict__ pairs,
                                                   int* __restrict__ bucket_fill,
                                                   int E, int CAP) {
    constexpr int EPB = 4096, EPT = 16;
    __shared__ int cnt[512];
    __shared__ int base_[512];
    __shared__ int gb[512];
    __shared__ int s2[256];
    __shared__ unsigned lp[EPB];
    const int t = threadIdx.x;
    const int start = blockIdx.x * EPB;
    const int nE = min(EPB, E - start);
    cnt[t] = 0;
    cnt[t + 256] = 0;
    __syncthreads();

    unsigned pk[EPT];
    unsigned short bk[EPT], loc[EPT];
    const bool is64 = (*flag != 0);
#pragma unroll
    for (int j = 0; j < EPT; ++j) {
        const int i = start + t + j * 256;
        if (i - start < nE) {
            unsigned ss, dd;
            if (is64) {
                ss = (unsigned)((const long long*)ebuf)[i];
                dd = (unsigned)((const long long*)ebuf)[(size_t)E + i];
            } else {
                ss = ((const unsigned*)ebuf)[i];
                dd = ((const unsigned*)ebuf)[(size_t)E + i];
            }
            const int b = dd >> 8;
            pk[j] = ((dd & 255u) << 24) | ss;
            bk[j] = (unsigned short)b;
            loc[j] = (unsigned short)atomicAdd(&cnt[b], 1);
        }
    }
    __syncthreads();
    // exclusive scan of 512 bucket counts by 256 threads (2 per thread)
    const int a = cnt[2 * t], b_ = cnt[2 * t + 1];
    s2[t] = a + b_;
    __syncthreads();
    for (int off = 1; off < 256; off <<= 1) {
        const int x = (t >= off) ? s2[t - off] : 0;
        __syncthreads();
        s2[t] += x;
        __syncthreads();
    }
    const int ex = s2[t] - a - b_;
    base_[2 * t] = ex;
    base_[2 * t + 1] = ex + a;
    __syncthreads();
    // reorder into LDS, bucket-grouped
#pragma unroll
    for (int j = 0; j < EPT; ++j) {
        const int i = start + t + j * 256;
        if (i - start < nE) lp[base_[bk[j]] + loc[j]] = pk[j];
    }
    // reserve global segment space: one atomic per non-empty bucket
    for (int b = t; b < 512; b += 256) {
        const int c = cnt[b];
        gb[b] = c ? atomicAdd(&bucket_fill[b], c) : 0;
    }
    __syncthreads();
    // locate bucket of each LDS slot via binary search over base_ (coalesced out)
    for (int i = t; i < nE; i += 256) {
        int lo = 0, hi = 511;
        while (lo < hi) {  // find last bucket with base_ <= i
            const int mid = (lo + hi + 1) >> 1;
            if (base_[mid] <= i) lo = mid; else hi = mid - 1;
        }
        pairs[(size_t)lo * CAP + gb[lo] + (i - base_[lo])] = lp[i];
    }
}

// ---------------- CSR build, phase 2: per-bucket scatter (L2-local) ----------------
__global__ __launch_bounds__(256) void bucket_scatter(const unsigned* __restrict__ pairs,
                                                      const int* __restrict__ bucket_fill,
                                                      int* __restrict__ rowbeg,
                                                      int* __restrict__ degO,
                                                      unsigned* __restrict__ csrb,
                                                      int N, int CAP) {
    const int b = blockIdx.x;
    const int t = threadIdx.x;
    const int d0 = b << 8;
    const int cnt = bucket_fill[b];
    const size_t seg = (size_t)b * CAP;
    __shared__ int degw[256];
    __shared__ int offw[256];
    __shared__ int frw[256];
    degw[t] = 0;
    __syncthreads();
    for (int i = t; i < cnt; i += 256) {
        atomicAdd(&degw[pairs[seg + i] >> 24], 1);
    }
    __syncthreads();
    const int v = degw[t];
    offw[t] = v;
    __syncthreads();
    for (int off = 1; off < 256; off <<= 1) {
        const int x = (t >= off) ? offw[t - off] : 0;
        __syncthreads();
        offw[t] += x;
        __syncthreads();
    }
    const int ex = offw[t] - v;
    const int node = d0 + t;
    if (node < N) {
        rowbeg[node] = (int)(seg + ex);
        degO[node] = v;
    }
    frw[t] = ex;
    __syncthreads();
    for (int i = t; i < cnt; i += 256) {
        const unsigned p = pairs[seg + i];
        const int pos = atomicAdd(&frw[p >> 24], 1);
        csrb[seg + pos] = p & 0x00FFFFFFu;
    }
}

// ---------------- dtype conversions ----------------
__global__ void cvt_x(const float* __restrict__ x, unsigned short* __restrict__ hx, int N) {
    const int idx = blockIdx.x * blockDim.x + threadIdx.x;
    if (idx >= N * 16) return;
    const int n = idx >> 4;
    const int k4 = (idx & 15) * 4;
    const float4 v = *reinterpret_cast<const float4*>(x + (size_t)n * 64 + k4);
    ushort4 o;
    o.x = f2bf(v.x); o.y = f2bf(v.y); o.z = f2bf(v.z); o.w = f2bf(v.w);
    *reinterpret_cast<ushort4*>(hx + (size_t)n * 64 + k4) = o;
}

__global__ void cvt_w3(const float* __restrict__ Wl1, const float* __restrict__ Wr1,
                       const float* __restrict__ Wl2, const float* __restrict__ Wr2,
                       const float* __restrict__ Wl3, const float* __restrict__ Wr3,
                       unsigned short* __restrict__ wc1, unsigned short* __restrict__ wc2,
                       unsigned short* __restrict__ wc3) {
    const int idx = blockIdx.x * blockDim.x + threadIdx.x;  // 81920 total
    if (idx < 128 * 128) {
        const int j = idx >> 7, k = idx & 127;           // K2=128, KH=64
        const float v = (k < 64) ? Wl1[j * 64 + k] : Wr1[j * 64 + k - 64];
        wc1[idx] = f2bf(v);
    } else if (idx < 128 * 128 + 128 * 256) {
        const int r = idx - 128 * 128;
        const int j = r >> 8, k = r & 255;               // K2=256, KH=128
        const float v = (k < 128) ? Wl2[j * 128 + k] : Wr2[j * 128 + k - 128];
        wc2[r] = f2bf(v);
    } else if (idx < 128 * 128 + 2 * 128 * 256) {
        const int r = idx - 128 * 128 - 128 * 256;
        const int j = r >> 8, k = r & 255;
        const float v = (k < 128) ? Wl3[j * 128 + k] : Wr3[j * 128 + k - 128];
        wc3[r] = f2bf(v);
    }
}

// ---------------- mean aggregation (bf16, compact stride=D), VALU-trimmed ----------------
// One wave per node, 16 rows in flight per pass. Per pass:
//  - lanes 0..15 cooperatively load the 16 csrb indices (one 64B line),
//    broadcast to consumers via __shfl (replaces 4 per-lane scalar gathers);
//  - out-of-range loads redirect to a zeroed dummy row (pointer cndmask)
//    instead of zero-init + predicated skip.
template <int D>
__global__ __launch_bounds__(256) void agg_bf16(const unsigned short* __restrict__ src,
                                                unsigned short* __restrict__ dst,
                                                const int* __restrict__ rowbeg,
                                                const int* __restrict__ degO,
                                                const unsigned* __restrict__ csrb,
                                                const unsigned short* __restrict__ zrow,
                                                int N) {
    constexpr int LPR = D / 8;            // lanes per row: 16 (D=128), 8 (D=64)
    constexpr int GRP = 64 / LPR;         // row groups per pass: 4, 8
    constexpr int J = 16 / GRP;           // rows per group per pass: 4, 2
    const int gid = blockIdx.x * blockDim.x + threadIdx.x;
    const int node = gid >> 6;
    const int lane = gid & 63;
    if (node >= N) return;
    const int beg = rowbeg[node];
    const int dg = degO[node];
    const int end = beg + dg;
    const int g = lane / LPR;
    const int m = lane % LPR;

    float acc[8] = {0.f, 0.f, 0.f, 0.f, 0.f, 0.f, 0.f, 0.f};

    for (int k0 = beg; k0 < end; k0 += 16) {
        // cooperative index fetch: lanes 0..15 hold csrb[k0 .. k0+15] (clamped)
        const int il = min(k0 + (lane & 15), end - 1);
        const int myidx = (int)csrb[il];
        short8 v[J];
#pragma unroll
        for (int j = 0; j < J; ++j) {
            const int kk = k0 + g + j * GRP;
            const int s = __shfl(myidx, g + j * GRP);
            const unsigned short* p = (kk < end) ? (src + (size_t)s * D) : zrow;
            v[j] = *reinterpret_cast<const short8*>(p + m * 8);
        }
#pragma unroll
        for (int j = 0; j < J; ++j) {
            const unsigned* u = reinterpret_cast<const unsigned*>(&v[j]);
#pragma unroll
            for (int q = 0; q < 4; ++q) {
                union { unsigned u; float f; } lo{u[q] << 16}, hi{u[q] & 0xffff0000u};
                acc[2 * q]     += lo.f;
                acc[2 * q + 1] += hi.f;
            }
        }
    }

    // reduce across row-groups (high lane bits above LPR)
#pragma unroll
    for (int mask = LPR; mask < 64; mask <<= 1) {
#pragma unroll
        for (int j = 0; j < 8; ++j) acc[j] += __shfl_xor(acc[j], mask);
    }

    if (lane < LPR) {
        const float inv = 1.0f / fmaxf((float)dg, 1.0f);
        unsigned o[4];
#pragma unroll
        for (int j = 0; j < 4; ++j) {
            o[j] = ((unsigned)f2bf(acc[2 * j + 1] * inv) << 16) | (unsigned)f2bf(acc[2 * j] * inv);
        }
        *reinterpret_cast<uint4*>(dst + (size_t)node * D + m * 8) =
            make_uint4(o[0], o[1], o[2], o[3]);
    }
}

// ---------------- MFMA GEMM: OUT = relu([A0|A1] @ W^T + b), split-K input ----------------
template <int DIN>
__global__ __launch_bounds__(256) void mfma_gemm(const unsigned short* __restrict__ A0,
                                                 const unsigned short* __restrict__ A1,
                                                 const unsigned short* __restrict__ W,
                                                 const float* __restrict__ bias,
                                                 unsigned short* __restrict__ OUT,
                                                 int N) {
    constexpr int K2 = 2 * DIN;
    const int tid = threadIdx.x;
    const int wid = tid >> 6;
    const int lane = tid & 63;
    const int m0 = blockIdx.x * 128;
    const int wm = m0 + wid * 32;
    const int lrow = lane & 15;
    const int kb = (lane >> 4) * 8;

    f32x4 acc[2][8];
#pragma unroll
    for (int i = 0; i < 2; ++i)
#pragma unroll
        for (int j = 0; j < 8; ++j) acc[i][j] = {0.f, 0.f, 0.f, 0.f};

    const int arow0 = wm + lrow;
    const int arow1 = wm + 16 + lrow;

#pragma unroll
    for (int k0 = 0; k0 < K2; k0 += 32) {
        const unsigned short* __restrict__ Ap = (k0 < DIN) ? A0 : A1;
        const int kc = (k0 < DIN) ? k0 : (k0 - DIN);
        short8 a0 = {0, 0, 0, 0, 0, 0, 0, 0}, a1 = a0;
        if (arow0 < N) a0 = *reinterpret_cast<const short8*>(Ap + (size_t)arow0 * DIN + kc + kb);
        if (arow1 < N) a1 = *reinterpret_cast<const short8*>(Ap + (size_t)arow1 * DIN + kc + kb);
        short8 b[8];
#pragma unroll
        for (int jb = 0; jb < 8; ++jb) {
            const int wrow = jb * 16 + lrow;
            b[jb] = *reinterpret_cast<const short8*>(W + (size_t)wrow * K2 + k0 + kb);
        }
#pragma unroll
        for (int jb = 0; jb < 8; ++jb) {
            acc[0][jb] = __builtin_amdgcn_mfma_f32_16x16x32_bf16(a0, b[jb], acc[0][jb], 0, 0, 0);
            acc[1][jb] = __builtin_amdgcn_mfma_f32_16x16x32_bf16(a1, b[jb], acc[1][jb], 0, 0, 0);
        }
    }

    float bias_r[8];
#pragma unroll
    for (int jb = 0; jb < 8; ++jb) bias_r[jb] = bias[jb * 16 + lrow];

    const int rbase = (lane >> 4) * 4;
#pragma unroll
    for (int i = 0; i < 2; ++i) {
#pragma unroll
        for (int r = 0; r < 4; ++r) {
            const int row = wm + i * 16 + rbase + r;
            if (row < N) {
                unsigned short* o = OUT + (size_t)row * HID + lrow;
#pragma unroll
                for (int jb = 0; jb < 8; ++jb) {
                    const float v = fmaxf(acc[i][jb][r] + bias_r[jb], 0.f);
                    o[jb * 16] = f2bf(v);
                }
            }
        }
    }
}

// ---------------- global mean pool + output head ----------------
__global__ __launch_bounds__(128) void pool_kernel(const unsigned short* __restrict__ H,
                                                   const int* __restrict__ batch,
                                                   const float* __restrict__ Wout,
                                                   const float* __restrict__ bout,
                                                   float* __restrict__ out, int N, int G) {
    const int g = blockIdx.x;
    const int t = threadIdx.x;
    int lo = 0, hi = N;
    while (lo < hi) {
        const int mid = (lo + hi) >> 1;
        if (batch[mid] < g) lo = mid + 1; else hi = mid;
    }
    const int start = lo;
    hi = N;
    while (lo < hi) {
        const int mid = (lo + hi) >> 1;
        if (batch[mid] < g + 1) lo = mid + 1; else hi = mid;
    }
    const int end = lo;
    float acc = 0.f;
    for (int n = start; n < end; ++n) acc += bf2f(H[(size_t)n * HID + t]);
    const float inv = 1.0f / fmaxf((float)(end - start), 1.0f);
    __shared__ float pl[HID];
    pl[t] = acc * inv;
    __syncthreads();
    if (t < TASKS) {
        float dot = bout[t];
        const float* w = Wout + t * HID;
        for (int k = 0; k < HID; ++k) dot = fmaf(pl[k], w[k], dot);
        out[(size_t)g * TASKS + t] = dot;
    }
}

// ---------------- launcher ----------------
extern "C" void kernel_launch(void* const* d_in, const int* in_sizes, int n_in,
                              void* d_out, int out_size, void* d_ws, size_t ws_size,
                              hipStream_t stream) {
    const float* x    = (const float*)d_in[0];
    const void*  e    = d_in[1];
    const void*  bt   = d_in[2];
    const float* Wl1  = (const float*)d_in[3];
    const float* bl1  = (const float*)d_in[4];
    const float* Wr1  = (const float*)d_in[5];
    const float* Wl2  = (const float*)d_in[6];
    const float* bl2  = (const float*)d_in[7];
    const float* Wr2  = (const float*)d_in[8];
    const float* Wl3  = (const float*)d_in[9];
    const float* bl3  = (const float*)d_in[10];
    const float* Wr3  = (const float*)d_in[11];
    const float* Wout = (const float*)d_in[12];
    const float* bout = (const float*)d_in[13];
    float* out = (float*)d_out;

    const int N = in_sizes[0] / 64;   // requires N <= 131072 (bucket = dst>>8) and N < 2^24 (packing)
    const int E = in_sizes[1] / 2;
    const int G = out_size / TASKS;
    const int NB = (N + 255) >> 8;
    const int CAP = 6144;             // per-bucket capacity; mean ~3200 for this input, +52 sigma

    char* base = (char*)d_ws;
    size_t off = 0;
    auto alloc = [&](size_t bytes) -> void* {
        void* p = base + off;
        off += (bytes + 255) & ~(size_t)255;
        return p;
    };
    int* flag        = (int*)alloc(256);
    unsigned short* zrow = (unsigned short*)alloc(256);   // zeroed dummy row (256B)
    int* b32         = (int*)alloc((size_t)N * 4);
    int* bucket_fill = (int*)alloc((size_t)NB * 4);
    int* rowbeg      = (int*)alloc((size_t)N * 4);
    int* degO        = (int*)alloc((size_t)N * 4);
    unsigned* pairs  = (unsigned*)alloc((size_t)NB * CAP * 4);
    unsigned* csrb   = (unsigned*)alloc((size_t)NB * CAP * 4);
    unsigned short* wc1 = (unsigned short*)alloc((size_t)128 * 128 * 2);
    unsigned short* wc2 = (unsigned short*)alloc((size_t)128 * 256 * 2);
    unsigned short* wc3 = (unsigned short*)alloc((size_t)128 * 256 * 2);
    unsigned short* hx = (unsigned short*)alloc((size_t)N * 64 * 2);    // compact x
    unsigned short* a1 = (unsigned short*)alloc((size_t)N * 64 * 2);    // compact agg1
    unsigned short* h1 = (unsigned short*)alloc((size_t)N * 128 * 2);
    unsigned short* a2 = (unsigned short*)alloc((size_t)N * 128 * 2);
    unsigned short* h2 = (unsigned short*)alloc((size_t)N * 128 * 2);
    unsigned short* a3 = (unsigned short*)alloc((size_t)N * 128 * 2);
    unsigned short* h3 = (unsigned short*)alloc((size_t)N * 128 * 2);
    (void)ws_size;
    (void)n_in;

    hipMemsetAsync(bucket_fill, 0, (size_t)NB * 4, stream);
    hipMemsetAsync(zrow, 0, 256, stream);

    detect_i64<<<1, 256, 0, stream>>>((const unsigned int*)e, flag);
    convert_batch<<<(N + 255) / 256, 256, 0, stream>>>(bt, flag, b32, N);
    bin_convert<<<(E + 4095) / 4096, 256, 0, stream>>>(e, flag, pairs, bucket_fill, E, CAP);
    bucket_scatter<<<NB, 256, 0, stream>>>(pairs, bucket_fill, rowbeg, degO, csrb, N, CAP);

    cvt_x<<<(N * 16 + 255) / 256, 256, 0, stream>>>(x, hx, N);
    cvt_w3<<<(81920 + 255) / 256, 256, 0, stream>>>(Wl1, Wr1, Wl2, Wr2, Wl3, Wr3, wc1, wc2, wc3);

    const int aggBlocks = (int)(((size_t)N * 64 + 255) / 256);
    const int gemmBlocks = (N + 127) / 128;

    // layer 1
    agg_bf16<64><<<aggBlocks, 256, 0, stream>>>(hx, a1, rowbeg, degO, csrb, zrow, N);
    mfma_gemm<64><<<gemmBlocks, 256, 0, stream>>>(hx, a1, wc1, bl1, h1, N);
    // layer 2
    agg_bf16<128><<<aggBlocks, 256, 0, stream>>>(h1, a2, rowbeg, degO, csrb, zrow, N);
    mfma_gemm<128><<<gemmBlocks, 256, 0, stream>>>(h1, a2, wc2, bl2, h2, N);
    // layer 3
    agg_bf16<128><<<aggBlocks, 256, 0, stream>>>(h2, a3, rowbeg, degO, csrb, zrow, N);
    mfma_gemm<128><<<gemmBlocks, 256, 0, stream>>>(h2, a3, wc3, bl3, h3, N);

    pool_kernel<<<G, 128, 0, stream>>>(h3, b32, Wout, bout, out, N, G);
}